// Round 1
// baseline (3185.964 us; speedup 1.0000x reference)
//
#include <hip/hip_runtime.h>

constexpr int kNodes = 50000;
constexpr int kEdges = 800000;
constexpr int kNF  = 64;
constexpr int kHid = 64;

// ---------------------------------------------------------------------------
// Edge kernel: one thread per edge.
// Computes radial features, 2-layer edge MLP (131->64->64), coord head
// (64->64->1), then atomically scatters m (64), trans (3), and count (1)
// into per-node accumulators by `row`.
// Weight accesses are lane-uniform (loop-index addressing) -> scalar loads.
// ---------------------------------------------------------------------------
__global__ __launch_bounds__(256) void egnn_edge_kernel(
    const float* __restrict__ h, const float* __restrict__ coord,
    const float* __restrict__ vel,
    const int* __restrict__ rows, const int* __restrict__ cols,
    const float* __restrict__ e_w1, const float* __restrict__ e_b1,
    const float* __restrict__ e_w2, const float* __restrict__ e_b2,
    const float* __restrict__ c_w1, const float* __restrict__ c_b1,
    const float* __restrict__ c_w,
    float* __restrict__ agg, float* __restrict__ seg, float* __restrict__ cnt)
{
  int e = blockIdx.x * 256 + threadIdx.x;
  if (e >= kEdges) return;
  int r = rows[e];
  int c = cols[e];

  // radial features
  float cd0 = coord[r * 3 + 0] - coord[c * 3 + 0];
  float cd1 = coord[r * 3 + 1] - coord[c * 3 + 1];
  float cd2 = coord[r * 3 + 2] - coord[c * 3 + 2];
  float vd0 = vel[r * 3 + 0] - vel[c * 3 + 0];
  float vd1 = vel[r * 3 + 1] - vel[c * 3 + 1];
  float vd2 = vel[r * 3 + 2] - vel[c * 3 + 2];
  float fx = sqrtf(cd0 * cd0 + cd1 * cd1 + cd2 * cd2);
  float fv = sqrtf(vd0 * vd0 + vd1 * vd1 + vd2 * vd2);
  float fxv = (cd0 * vd0 + cd1 * vd1 + cd2 * vd2) / (fx * fv);

  const float4* h4 = reinterpret_cast<const float4*>(h);

  // ---- layer 1: edge_in(131) @ e_w1 -> m1(64), relu ----
  float m1[kHid];
#pragma unroll
  for (int j = 0; j < kHid; j++) m1[j] = e_b1[j];

  // source node features, rows 0..63 of e_w1
#pragma unroll 4
  for (int k4 = 0; k4 < 16; k4++) {
    float4 x4 = h4[r * 16 + k4];
    float xs[4] = {x4.x, x4.y, x4.z, x4.w};
#pragma unroll
    for (int u = 0; u < 4; u++) {
      float x = xs[u];
      const float* w = e_w1 + (k4 * 4 + u) * kHid;
#pragma unroll
      for (int j = 0; j < kHid; j++) m1[j] += x * w[j];
    }
  }
  // target node features, rows 64..127 of e_w1
#pragma unroll 4
  for (int k4 = 0; k4 < 16; k4++) {
    float4 x4 = h4[c * 16 + k4];
    float xs[4] = {x4.x, x4.y, x4.z, x4.w};
#pragma unroll
    for (int u = 0; u < 4; u++) {
      float x = xs[u];
      const float* w = e_w1 + (64 + k4 * 4 + u) * kHid;
#pragma unroll
      for (int j = 0; j < kHid; j++) m1[j] += x * w[j];
    }
  }
  // radial features, rows 128..130 of e_w1
  {
    float rad[3] = {fx, fv, fxv};
#pragma unroll
    for (int u = 0; u < 3; u++) {
      float x = rad[u];
      const float* w = e_w1 + (128 + u) * kHid;
#pragma unroll
      for (int j = 0; j < kHid; j++) m1[j] += x * w[j];
    }
  }
#pragma unroll
  for (int j = 0; j < kHid; j++) m1[j] = fmaxf(m1[j], 0.0f);

  // ---- layer 2: m1(64) @ e_w2 -> m2(64), relu ----
  float m2[kHid];
#pragma unroll
  for (int j = 0; j < kHid; j++) m2[j] = e_b2[j];
#pragma unroll
  for (int k = 0; k < kHid; k++) {
    float x = m1[k];
    const float* w = e_w2 + k * kHid;
#pragma unroll
    for (int j = 0; j < kHid; j++) m2[j] += x * w[j];
  }
#pragma unroll
  for (int j = 0; j < kHid; j++) m2[j] = fmaxf(m2[j], 0.0f);

  // ---- coord head: relu(m2 @ c_w1 + c_b1) @ c_w -> scalar s ----
  {
    float t[kHid];
#pragma unroll
    for (int j = 0; j < kHid; j++) t[j] = c_b1[j];
#pragma unroll
    for (int k = 0; k < kHid; k++) {
      float x = m2[k];
      const float* w = c_w1 + k * kHid;
#pragma unroll
      for (int j = 0; j < kHid; j++) t[j] += x * w[j];
    }
    float s = 0.0f;
#pragma unroll
    for (int j = 0; j < kHid; j++) s += fmaxf(t[j], 0.0f) * c_w[j];

    // trans = clip(coord_diff * s, +-100), scatter by row
    float t0 = fminf(fmaxf(cd0 * s, -100.0f), 100.0f);
    float t1 = fminf(fmaxf(cd1 * s, -100.0f), 100.0f);
    float t2 = fminf(fmaxf(cd2 * s, -100.0f), 100.0f);
    atomicAdd(&seg[r * 3 + 0], t0);
    atomicAdd(&seg[r * 3 + 1], t1);
    atomicAdd(&seg[r * 3 + 2], t2);
    atomicAdd(&cnt[r], 1.0f);
  }

  // scatter m2 into agg by row
#pragma unroll
  for (int j = 0; j < kHid; j++) atomicAdd(&agg[r * kHid + j], m2[j]);
}

// ---------------------------------------------------------------------------
// Node kernel: one thread per node.
// h_out = relu([h, agg] @ n_w1 + n_b1) @ n_w2 + n_b2
// coord_out = seg / max(cnt, 1)
// ---------------------------------------------------------------------------
__global__ __launch_bounds__(256) void egnn_node_kernel(
    const float* __restrict__ h, const float* __restrict__ agg,
    const float* __restrict__ seg, const float* __restrict__ cnt,
    const float* __restrict__ n_w1, const float* __restrict__ n_b1,
    const float* __restrict__ n_w2, const float* __restrict__ n_b2,
    float* __restrict__ h_out, float* __restrict__ coord_out)
{
  int i = blockIdx.x * 256 + threadIdx.x;
  if (i >= kNodes) return;

  const float4* h4 = reinterpret_cast<const float4*>(h);
  const float4* a4 = reinterpret_cast<const float4*>(agg);

  float t1[kHid];
#pragma unroll
  for (int j = 0; j < kHid; j++) t1[j] = n_b1[j];

#pragma unroll 4
  for (int k4 = 0; k4 < 16; k4++) {
    float4 x4 = h4[i * 16 + k4];
    float xs[4] = {x4.x, x4.y, x4.z, x4.w};
#pragma unroll
    for (int u = 0; u < 4; u++) {
      float x = xs[u];
      const float* w = n_w1 + (k4 * 4 + u) * kHid;
#pragma unroll
      for (int j = 0; j < kHid; j++) t1[j] += x * w[j];
    }
  }
#pragma unroll 4
  for (int k4 = 0; k4 < 16; k4++) {
    float4 x4 = a4[i * 16 + k4];
    float xs[4] = {x4.x, x4.y, x4.z, x4.w};
#pragma unroll
    for (int u = 0; u < 4; u++) {
      float x = xs[u];
      const float* w = n_w1 + (64 + k4 * 4 + u) * kHid;
#pragma unroll
      for (int j = 0; j < kHid; j++) t1[j] += x * w[j];
    }
  }
#pragma unroll
  for (int j = 0; j < kHid; j++) t1[j] = fmaxf(t1[j], 0.0f);

  float out[kHid];
#pragma unroll
  for (int j = 0; j < kHid; j++) out[j] = n_b2[j];
#pragma unroll
  for (int k = 0; k < kHid; k++) {
    float x = t1[k];
    const float* w = n_w2 + k * kHid;
#pragma unroll
    for (int j = 0; j < kHid; j++) out[j] += x * w[j];
  }

  float4* ho4 = reinterpret_cast<float4*>(h_out);
#pragma unroll
  for (int j4 = 0; j4 < 16; j4++) {
    float4 v;
    v.x = out[j4 * 4 + 0];
    v.y = out[j4 * 4 + 1];
    v.z = out[j4 * 4 + 2];
    v.w = out[j4 * 4 + 3];
    ho4[i * 16 + j4] = v;
  }

  float cc = fmaxf(cnt[i], 1.0f);
  coord_out[i * 3 + 0] = seg[i * 3 + 0] / cc;
  coord_out[i * 3 + 1] = seg[i * 3 + 1] / cc;
  coord_out[i * 3 + 2] = seg[i * 3 + 2] / cc;
}

extern "C" void kernel_launch(void* const* d_in, const int* in_sizes, int n_in,
                              void* d_out, int out_size, void* d_ws, size_t ws_size,
                              hipStream_t stream) {
  const float* h     = (const float*)d_in[0];
  const float* coord = (const float*)d_in[1];
  const float* vel   = (const float*)d_in[2];
  const int* edge_index = (const int*)d_in[3];
  const float* e_w1 = (const float*)d_in[4];
  const float* e_b1 = (const float*)d_in[5];
  const float* e_w2 = (const float*)d_in[6];
  const float* e_b2 = (const float*)d_in[7];
  const float* n_w1 = (const float*)d_in[8];
  const float* n_b1 = (const float*)d_in[9];
  const float* n_w2 = (const float*)d_in[10];
  const float* n_b2 = (const float*)d_in[11];
  const float* c_w1 = (const float*)d_in[12];
  const float* c_b1 = (const float*)d_in[13];
  const float* c_w  = (const float*)d_in[14];

  const int* rows = edge_index;           // edge_index[0]
  const int* cols = edge_index + kEdges;  // edge_index[1]

  // workspace layout: agg [N*64] | seg [N*3] | cnt [N]
  float* agg = (float*)d_ws;
  float* seg = agg + (size_t)kNodes * kHid;
  float* cnt = seg + (size_t)kNodes * 3;
  size_t ws_floats = (size_t)kNodes * (kHid + 3 + 1);
  hipMemsetAsync(d_ws, 0, ws_floats * sizeof(float), stream);

  float* h_out = (float*)d_out;
  float* coord_out = h_out + (size_t)kNodes * kNF;

  egnn_edge_kernel<<<(kEdges + 255) / 256, 256, 0, stream>>>(
      h, coord, vel, rows, cols, e_w1, e_b1, e_w2, e_b2, c_w1, c_b1, c_w,
      agg, seg, cnt);

  egnn_node_kernel<<<(kNodes + 255) / 256, 256, 0, stream>>>(
      h, agg, seg, cnt, n_w1, n_b1, n_w2, n_b2, h_out, coord_out);
}

// Round 2
// 1063.885 us; speedup vs baseline: 2.9946x; 2.9946x over previous
//
#include <hip/hip_runtime.h>

constexpr int kNodes = 50000;
constexpr int kEdges = 800000;
constexpr int kNF  = 64;
constexpr int kHid = 64;

// ---------------------------------------------------------------------------
// CSR build: histogram -> exclusive scan -> cursor scatter
// ---------------------------------------------------------------------------
__global__ __launch_bounds__(256) void hist_kernel(const int* __restrict__ rows,
                                                   int* __restrict__ hist) {
  int e = blockIdx.x * 256 + threadIdx.x;
  if (e < kEdges) atomicAdd(&hist[rows[e]], 1);
}

__global__ __launch_bounds__(1024) void scan_kernel(const int* __restrict__ hist,
                                                    int* __restrict__ rowstart) {
  __shared__ int sdata[1024];
  __shared__ int s_run;
  int t = threadIdx.x;
  if (t == 0) s_run = 0;
  __syncthreads();
  for (int base = 0; base < kNodes; base += 1024) {
    int v = (base + t < kNodes) ? hist[base + t] : 0;
    sdata[t] = v;
    __syncthreads();
    int acc = v;
    for (int off = 1; off < 1024; off <<= 1) {
      int x = (t >= off) ? sdata[t - off] : 0;
      __syncthreads();
      acc += x;
      sdata[t] = acc;
      __syncthreads();
    }
    int run = s_run;
    if (base + t < kNodes) rowstart[base + t] = run + acc - v;  // exclusive
    __syncthreads();
    if (t == 1023) s_run = run + acc;  // acc at t=1023 is the chunk total
    __syncthreads();
  }
  if (t == 0) rowstart[kNodes] = s_run;
}

__global__ __launch_bounds__(256) void scatter_kernel(const int* __restrict__ rows,
                                                      const int* __restrict__ rowstart,
                                                      int* __restrict__ cursor,
                                                      int* __restrict__ eids) {
  int e = blockIdx.x * 256 + threadIdx.x;
  if (e >= kEdges) return;
  int r = rows[e];
  int p = atomicAdd(&cursor[r], 1);
  eids[rowstart[r] + p] = e;
}

// ---------------------------------------------------------------------------
// Edge kernel: one thread per edge. MODE 0: write m (fp16) + trans (fp32x4).
// MODE 1 (fallback): atomic scatter like round 1.
// Weight accesses are lane-uniform -> scalar loads.
// ---------------------------------------------------------------------------
template <int MODE>
__global__ __launch_bounds__(256) void egnn_edge_kernel(
    const float* __restrict__ h, const float* __restrict__ coord,
    const float* __restrict__ vel,
    const int* __restrict__ rows, const int* __restrict__ cols,
    const float* __restrict__ e_w1, const float* __restrict__ e_b1,
    const float* __restrict__ e_w2, const float* __restrict__ e_b2,
    const float* __restrict__ c_w1, const float* __restrict__ c_b1,
    const float* __restrict__ c_w,
    _Float16* __restrict__ mbuf, float* __restrict__ transbuf,
    float* __restrict__ agg, float* __restrict__ seg, float* __restrict__ cnt)
{
  int e = blockIdx.x * 256 + threadIdx.x;
  if (e >= kEdges) return;
  int r = rows[e];
  int c = cols[e];

  float cd0 = coord[r * 3 + 0] - coord[c * 3 + 0];
  float cd1 = coord[r * 3 + 1] - coord[c * 3 + 1];
  float cd2 = coord[r * 3 + 2] - coord[c * 3 + 2];
  float vd0 = vel[r * 3 + 0] - vel[c * 3 + 0];
  float vd1 = vel[r * 3 + 1] - vel[c * 3 + 1];
  float vd2 = vel[r * 3 + 2] - vel[c * 3 + 2];
  float fx = sqrtf(cd0 * cd0 + cd1 * cd1 + cd2 * cd2);
  float fv = sqrtf(vd0 * vd0 + vd1 * vd1 + vd2 * vd2);
  float fxv = (cd0 * vd0 + cd1 * vd1 + cd2 * vd2) / (fx * fv);

  const float4* h4 = reinterpret_cast<const float4*>(h);

  // ---- layer 1: edge_in(131) @ e_w1 -> m1(64), relu ----
  float m1[kHid];
#pragma unroll
  for (int j = 0; j < kHid; j++) m1[j] = e_b1[j];

#pragma unroll 4
  for (int k4 = 0; k4 < 16; k4++) {
    float4 x4 = h4[r * 16 + k4];
    float xs[4] = {x4.x, x4.y, x4.z, x4.w};
#pragma unroll
    for (int u = 0; u < 4; u++) {
      float x = xs[u];
      const float* w = e_w1 + (k4 * 4 + u) * kHid;
#pragma unroll
      for (int j = 0; j < kHid; j++) m1[j] += x * w[j];
    }
  }
#pragma unroll 4
  for (int k4 = 0; k4 < 16; k4++) {
    float4 x4 = h4[c * 16 + k4];
    float xs[4] = {x4.x, x4.y, x4.z, x4.w};
#pragma unroll
    for (int u = 0; u < 4; u++) {
      float x = xs[u];
      const float* w = e_w1 + (64 + k4 * 4 + u) * kHid;
#pragma unroll
      for (int j = 0; j < kHid; j++) m1[j] += x * w[j];
    }
  }
  {
    float rad[3] = {fx, fv, fxv};
#pragma unroll
    for (int u = 0; u < 3; u++) {
      float x = rad[u];
      const float* w = e_w1 + (128 + u) * kHid;
#pragma unroll
      for (int j = 0; j < kHid; j++) m1[j] += x * w[j];
    }
  }
#pragma unroll
  for (int j = 0; j < kHid; j++) m1[j] = fmaxf(m1[j], 0.0f);

  // ---- layer 2: m1 @ e_w2 -> m2, relu ----
  float m2[kHid];
#pragma unroll
  for (int j = 0; j < kHid; j++) m2[j] = e_b2[j];
#pragma unroll
  for (int k = 0; k < kHid; k++) {
    float x = m1[k];
    const float* w = e_w2 + k * kHid;
#pragma unroll
    for (int j = 0; j < kHid; j++) m2[j] += x * w[j];
  }
#pragma unroll
  for (int j = 0; j < kHid; j++) m2[j] = fmaxf(m2[j], 0.0f);

  // ---- coord head: relu(m2 @ c_w1 + c_b1) @ c_w -> scalar s ----
  float s = 0.0f;
  {
    float t[kHid];
#pragma unroll
    for (int j = 0; j < kHid; j++) t[j] = c_b1[j];
#pragma unroll
    for (int k = 0; k < kHid; k++) {
      float x = m2[k];
      const float* w = c_w1 + k * kHid;
#pragma unroll
      for (int j = 0; j < kHid; j++) t[j] += x * w[j];
    }
#pragma unroll
    for (int j = 0; j < kHid; j++) s += fmaxf(t[j], 0.0f) * c_w[j];
  }
  float t0 = fminf(fmaxf(cd0 * s, -100.0f), 100.0f);
  float t1 = fminf(fmaxf(cd1 * s, -100.0f), 100.0f);
  float t2 = fminf(fmaxf(cd2 * s, -100.0f), 100.0f);

  if constexpr (MODE == 0) {
    alignas(16) _Float16 mh[kHid];
#pragma unroll
    for (int j = 0; j < kHid; j++) mh[j] = (_Float16)m2[j];
    float4* dst = reinterpret_cast<float4*>(mbuf + (size_t)e * kHid);
    const float4* src = reinterpret_cast<const float4*>(mh);
#pragma unroll
    for (int q = 0; q < 8; q++) dst[q] = src[q];
    reinterpret_cast<float4*>(transbuf)[e] = make_float4(t0, t1, t2, 0.0f);
  } else {
    atomicAdd(&seg[r * 3 + 0], t0);
    atomicAdd(&seg[r * 3 + 1], t1);
    atomicAdd(&seg[r * 3 + 2], t2);
    atomicAdd(&cnt[r], 1.0f);
#pragma unroll
    for (int j = 0; j < kHid; j++) atomicAdd(&agg[r * kHid + j], m2[j]);
  }
}

// ---------------------------------------------------------------------------
// Gather kernel: one wave (64 lanes) per node. Lane j sums feature j of m
// over the node's CSR edge list; coord sums via lane-parallel + shuffle tree.
// ---------------------------------------------------------------------------
__global__ __launch_bounds__(256) void egnn_gather_kernel(
    const _Float16* __restrict__ mbuf, const float* __restrict__ transbuf,
    const int* __restrict__ rowstart, const int* __restrict__ eids,
    float* __restrict__ agg, float* __restrict__ coord_out)
{
  int node = blockIdx.x * 4 + (threadIdx.x >> 6);
  if (node >= kNodes) return;
  int lane = threadIdx.x & 63;
  int start = rowstart[node];
  int end = rowstart[node + 1];

  float a = 0.0f;
#pragma unroll 4
  for (int k = start; k < end; k++) {
    int eid = eids[k];                       // wave-uniform -> s_load
    a += (float)mbuf[(size_t)eid * kHid + lane];  // 128B coalesced per edge
  }
  agg[(size_t)node * kHid + lane] = a;

  float t0 = 0.0f, t1 = 0.0f, t2 = 0.0f;
  for (int k = start + lane; k < end; k += 64) {
    int eid = eids[k];
    float4 tv = reinterpret_cast<const float4*>(transbuf)[eid];
    t0 += tv.x; t1 += tv.y; t2 += tv.z;
  }
#pragma unroll
  for (int m = 32; m >= 1; m >>= 1) {
    t0 += __shfl_xor(t0, m);
    t1 += __shfl_xor(t1, m);
    t2 += __shfl_xor(t2, m);
  }
  if (lane == 0) {
    float cc = fmaxf((float)(end - start), 1.0f);
    coord_out[(size_t)node * 3 + 0] = t0 / cc;
    coord_out[(size_t)node * 3 + 1] = t1 / cc;
    coord_out[(size_t)node * 3 + 2] = t2 / cc;
  }
}

// ---------------------------------------------------------------------------
// Node MLP: h_out = relu([h, agg] @ n_w1 + n_b1) @ n_w2 + n_b2
// ---------------------------------------------------------------------------
__device__ __forceinline__ void node_mlp(
    int i, const float* __restrict__ h, const float* __restrict__ agg,
    const float* __restrict__ n_w1, const float* __restrict__ n_b1,
    const float* __restrict__ n_w2, const float* __restrict__ n_b2,
    float* __restrict__ h_out)
{
  const float4* h4 = reinterpret_cast<const float4*>(h);
  const float4* a4 = reinterpret_cast<const float4*>(agg);

  float t1[kHid];
#pragma unroll
  for (int j = 0; j < kHid; j++) t1[j] = n_b1[j];

#pragma unroll 4
  for (int k4 = 0; k4 < 16; k4++) {
    float4 x4 = h4[i * 16 + k4];
    float xs[4] = {x4.x, x4.y, x4.z, x4.w};
#pragma unroll
    for (int u = 0; u < 4; u++) {
      float x = xs[u];
      const float* w = n_w1 + (k4 * 4 + u) * kHid;
#pragma unroll
      for (int j = 0; j < kHid; j++) t1[j] += x * w[j];
    }
  }
#pragma unroll 4
  for (int k4 = 0; k4 < 16; k4++) {
    float4 x4 = a4[i * 16 + k4];
    float xs[4] = {x4.x, x4.y, x4.z, x4.w};
#pragma unroll
    for (int u = 0; u < 4; u++) {
      float x = xs[u];
      const float* w = n_w1 + (64 + k4 * 4 + u) * kHid;
#pragma unroll
      for (int j = 0; j < kHid; j++) t1[j] += x * w[j];
    }
  }
#pragma unroll
  for (int j = 0; j < kHid; j++) t1[j] = fmaxf(t1[j], 0.0f);

  float out[kHid];
#pragma unroll
  for (int j = 0; j < kHid; j++) out[j] = n_b2[j];
#pragma unroll
  for (int k = 0; k < kHid; k++) {
    float x = t1[k];
    const float* w = n_w2 + k * kHid;
#pragma unroll
    for (int j = 0; j < kHid; j++) out[j] += x * w[j];
  }

  float4* ho4 = reinterpret_cast<float4*>(h_out);
#pragma unroll
  for (int j4 = 0; j4 < 16; j4++) {
    ho4[i * 16 + j4] = make_float4(out[j4 * 4 + 0], out[j4 * 4 + 1],
                                   out[j4 * 4 + 2], out[j4 * 4 + 3]);
  }
}

__global__ __launch_bounds__(256) void egnn_node_kernel(
    const float* __restrict__ h, const float* __restrict__ agg,
    const float* __restrict__ n_w1, const float* __restrict__ n_b1,
    const float* __restrict__ n_w2, const float* __restrict__ n_b2,
    float* __restrict__ h_out)
{
  int i = blockIdx.x * 256 + threadIdx.x;
  if (i >= kNodes) return;
  node_mlp(i, h, agg, n_w1, n_b1, n_w2, n_b2, h_out);
}

// Fallback node kernel (atomic path): also finishes coord mean.
__global__ __launch_bounds__(256) void egnn_node_fallback_kernel(
    const float* __restrict__ h, const float* __restrict__ agg,
    const float* __restrict__ seg, const float* __restrict__ cnt,
    const float* __restrict__ n_w1, const float* __restrict__ n_b1,
    const float* __restrict__ n_w2, const float* __restrict__ n_b2,
    float* __restrict__ h_out, float* __restrict__ coord_out)
{
  int i = blockIdx.x * 256 + threadIdx.x;
  if (i >= kNodes) return;
  node_mlp(i, h, agg, n_w1, n_b1, n_w2, n_b2, h_out);
  float cc = fmaxf(cnt[i], 1.0f);
  coord_out[i * 3 + 0] = seg[i * 3 + 0] / cc;
  coord_out[i * 3 + 1] = seg[i * 3 + 1] / cc;
  coord_out[i * 3 + 2] = seg[i * 3 + 2] / cc;
}

extern "C" void kernel_launch(void* const* d_in, const int* in_sizes, int n_in,
                              void* d_out, int out_size, void* d_ws, size_t ws_size,
                              hipStream_t stream) {
  const float* h     = (const float*)d_in[0];
  const float* coord = (const float*)d_in[1];
  const float* vel   = (const float*)d_in[2];
  const int* edge_index = (const int*)d_in[3];
  const float* e_w1 = (const float*)d_in[4];
  const float* e_b1 = (const float*)d_in[5];
  const float* e_w2 = (const float*)d_in[6];
  const float* e_b2 = (const float*)d_in[7];
  const float* n_w1 = (const float*)d_in[8];
  const float* n_b1 = (const float*)d_in[9];
  const float* n_w2 = (const float*)d_in[10];
  const float* n_b2 = (const float*)d_in[11];
  const float* c_w1 = (const float*)d_in[12];
  const float* c_b1 = (const float*)d_in[13];
  const float* c_w  = (const float*)d_in[14];

  const int* rows = edge_index;
  const int* cols = edge_index + kEdges;

  float* h_out = (float*)d_out;
  float* coord_out = h_out + (size_t)kNodes * kNF;

  // Workspace layout (bytes):
  //   mbuf   [E*64] fp16   : 102,400,000
  //   trans  [E*4]  fp32   :  12,800,000
  //   agg    [N*64] fp32   :  12,800,000
  //   eids   [E]    int    :   3,200,000
  //   hist   [N]    int    :     200,000
  //   cursor [N]    int    :     200,000
  //   rowstart [N+1] int   :     200,004
  const size_t off_mbuf   = 0;
  const size_t off_trans  = off_mbuf  + (size_t)kEdges * kHid * 2;
  const size_t off_agg    = off_trans + (size_t)kEdges * 4 * 4;
  const size_t off_eids   = off_agg   + (size_t)kNodes * kHid * 4;
  const size_t off_hist   = off_eids  + (size_t)kEdges * 4;
  const size_t off_cursor = off_hist  + (size_t)kNodes * 4;
  const size_t off_rowst  = off_cursor + (size_t)kNodes * 4;
  const size_t need = off_rowst + (size_t)(kNodes + 1) * 4;

  char* ws = (char*)d_ws;

  if (ws_size >= need) {
    _Float16* mbuf = (_Float16*)(ws + off_mbuf);
    float* transbuf = (float*)(ws + off_trans);
    float* agg      = (float*)(ws + off_agg);
    int* eids       = (int*)(ws + off_eids);
    int* hist       = (int*)(ws + off_hist);
    int* cursor     = (int*)(ws + off_cursor);
    int* rowstart   = (int*)(ws + off_rowst);

    // zero hist + cursor (contiguous)
    hipMemsetAsync(ws + off_hist, 0, (size_t)kNodes * 4 * 2, stream);

    hist_kernel<<<(kEdges + 255) / 256, 256, 0, stream>>>(rows, hist);
    scan_kernel<<<1, 1024, 0, stream>>>(hist, rowstart);
    scatter_kernel<<<(kEdges + 255) / 256, 256, 0, stream>>>(rows, rowstart, cursor, eids);

    egnn_edge_kernel<0><<<(kEdges + 255) / 256, 256, 0, stream>>>(
        h, coord, vel, rows, cols, e_w1, e_b1, e_w2, e_b2, c_w1, c_b1, c_w,
        mbuf, transbuf, nullptr, nullptr, nullptr);

    egnn_gather_kernel<<<(kNodes + 3) / 4, 256, 0, stream>>>(
        mbuf, transbuf, rowstart, eids, agg, coord_out);

    egnn_node_kernel<<<(kNodes + 255) / 256, 256, 0, stream>>>(
        h, agg, n_w1, n_b1, n_w2, n_b2, h_out);
  } else {
    // Fallback: atomic-scatter path (round-1 behavior)
    float* agg = (float*)d_ws;
    float* seg = agg + (size_t)kNodes * kHid;
    float* cnt = seg + (size_t)kNodes * 3;
    hipMemsetAsync(d_ws, 0, (size_t)kNodes * (kHid + 4) * sizeof(float), stream);

    egnn_edge_kernel<1><<<(kEdges + 255) / 256, 256, 0, stream>>>(
        h, coord, vel, rows, cols, e_w1, e_b1, e_w2, e_b2, c_w1, c_b1, c_w,
        nullptr, nullptr, agg, seg, cnt);

    egnn_node_fallback_kernel<<<(kNodes + 255) / 256, 256, 0, stream>>>(
        h, agg, seg, cnt, n_w1, n_b1, n_w2, n_b2, h_out, coord_out);
  }
}

// Round 3
// 388.451 us; speedup vs baseline: 8.2017x; 2.7388x over previous
//
#include <hip/hip_runtime.h>

constexpr int kNodes = 50000;
constexpr int kEdges = 800000;
constexpr int kNF  = 64;
constexpr int kHid = 64;

constexpr int LDA   = 168;  // sA row stride in f16 (pad 160->168: 2-way-free banks)
constexpr int WR1   = 168;  // w1t row stride (f16)
constexpr int WR2   = 72;   // w2t/w3t/sM row stride (f16)

typedef _Float16 f16x8 __attribute__((ext_vector_type(8)));
typedef float    f32x4 __attribute__((ext_vector_type(4)));

// ---------------------------------------------------------------------------
// Weight prep: transpose + f16-convert weights into ws (zero-padded K).
// w1t[j][k] = e_w1[k][j] (k<131), w2t[j][k]=e_w2[k][j], w3t[j][k]=c_w1[k][j]
// ---------------------------------------------------------------------------
__global__ __launch_bounds__(256) void prep_weights(
    const float* __restrict__ e_w1, const float* __restrict__ e_w2,
    const float* __restrict__ c_w1,
    _Float16* __restrict__ w1t, _Float16* __restrict__ w2t,
    _Float16* __restrict__ w3t)
{
  int t = blockIdx.x * 256 + threadIdx.x;
  int total = gridDim.x * 256;
  for (int idx = t; idx < 64 * WR1; idx += total) {
    int j = idx / WR1, k = idx % WR1;
    w1t[idx] = (k < 131) ? (_Float16)e_w1[k * 64 + j] : (_Float16)0.f;
  }
  for (int idx = t; idx < 64 * WR2; idx += total) {
    int j = idx / WR2, k = idx % WR2;
    w2t[idx] = (k < 64) ? (_Float16)e_w2[k * 64 + j] : (_Float16)0.f;
    w3t[idx] = (k < 64) ? (_Float16)c_w1[k * 64 + j] : (_Float16)0.f;
  }
}

// ---------------------------------------------------------------------------
// CSR build: histogram -> 3-stage scan -> cursor scatter
// ---------------------------------------------------------------------------
__global__ __launch_bounds__(256) void hist_kernel(const int* __restrict__ rows,
                                                   int* __restrict__ hist) {
  int e = blockIdx.x * 256 + threadIdx.x;
  if (e < kEdges) atomicAdd(&hist[rows[e]], 1);
}

__global__ __launch_bounds__(1024) void scan1(const int* __restrict__ hist,
                                              int* __restrict__ rowstart,
                                              int* __restrict__ bsum) {
  int t = threadIdx.x;
  int i = blockIdx.x * 1024 + t;
  int lane = t & 63, wv = t >> 6;
  int v = (i < kNodes) ? hist[i] : 0;
  int acc = v;
#pragma unroll
  for (int off = 1; off < 64; off <<= 1) {
    int u = __shfl_up(acc, off);
    if (lane >= off) acc += u;
  }
  __shared__ int wsum[16];
  if (lane == 63) wsum[wv] = acc;
  __syncthreads();
  if (t < 16) {
    int ws = wsum[t];
#pragma unroll
    for (int off = 1; off < 16; off <<= 1) {
      int u = __shfl_up(ws, off);
      if (lane >= off) ws += u;
    }
    wsum[t] = ws;
  }
  __syncthreads();
  int woff = (wv == 0) ? 0 : wsum[wv - 1];
  if (i < kNodes) rowstart[i] = woff + acc - v;  // block-local exclusive
  if (t == 1023) bsum[blockIdx.x] = wsum[15];
}

__global__ void scan2(const int* __restrict__ bsum, int* __restrict__ boff,
                      int* __restrict__ rowstart) {
  int lane = threadIdx.x;  // 64 threads
  const int nb = (kNodes + 1023) / 1024;
  int v = (lane < nb) ? bsum[lane] : 0;
  int acc = v;
#pragma unroll
  for (int off = 1; off < 64; off <<= 1) {
    int u = __shfl_up(acc, off);
    if (lane >= off) acc += u;
  }
  if (lane < nb) boff[lane] = acc - v;
  if (lane == nb - 1) rowstart[kNodes] = acc;
}

__global__ __launch_bounds__(1024) void scan3(int* __restrict__ rowstart,
                                              const int* __restrict__ boff) {
  int i = blockIdx.x * 1024 + threadIdx.x;
  if (i < kNodes) rowstart[i] += boff[blockIdx.x];
}

__global__ __launch_bounds__(256) void scatter_kernel(const int* __restrict__ rows,
                                                      const int* __restrict__ rowstart,
                                                      int* __restrict__ cursor,
                                                      int* __restrict__ eids) {
  int e = blockIdx.x * 256 + threadIdx.x;
  if (e >= kEdges) return;
  int r = rows[e];
  int p = atomicAdd(&cursor[r], 1);
  eids[rowstart[r] + p] = e;
}

// ---------------------------------------------------------------------------
// MFMA edge kernel. Block = 64 edges, 4 waves; wave owns 16 edges.
// Computes transposed layers D = W^T . X^T so edge index = lane&15 always:
//   A-operand = W^T rows (out j), from global f16 w*t buffers (L2-resident)
//   B-operand = features^T, from LDS (sA for layer 1, sM restage after)
// C/D layout (verified m89): col=lane&15 (edge), row=(lane>>4)*4+reg (out)
// A/B operand: row|col = lane&15, k = (lane>>4)*8 + e
// ---------------------------------------------------------------------------
__global__ __launch_bounds__(256) void egnn_edge_mfma(
    const float* __restrict__ h, const float* __restrict__ coord,
    const float* __restrict__ vel,
    const int* __restrict__ rows, const int* __restrict__ cols,
    const _Float16* __restrict__ w1t, const _Float16* __restrict__ w2t,
    const _Float16* __restrict__ w3t,
    const float* __restrict__ e_b1, const float* __restrict__ e_b2,
    const float* __restrict__ c_b1, const float* __restrict__ c_w,
    _Float16* __restrict__ mbuf, float* __restrict__ transbuf)
{
  __shared__ _Float16 sA[64][LDA];      // feature tile, f16, k in [0,160) used
  __shared__ _Float16 sM[4][16][WR2];   // per-wave inter-layer restage
  __shared__ float4 sCD[64];            // coord_diff per edge

  const int t = threadIdx.x;
  const int e_base = blockIdx.x * 64;

  // ---------------- stage: gather h[r], h[c], radial -> sA (f16) -----------
  {
    int edge = t >> 2, p = t & 3;
    int eid = e_base + edge;
    int r = rows[eid], c = cols[eid];
    const float4* h4 = reinterpret_cast<const float4*>(h);
#pragma unroll
    for (int i = 0; i < 4; i++) {
      float4 v = h4[r * 16 + p * 4 + i];
      union { _Float16 f[4]; uint2 u; } pk;
      pk.f[0] = (_Float16)v.x; pk.f[1] = (_Float16)v.y;
      pk.f[2] = (_Float16)v.z; pk.f[3] = (_Float16)v.w;
      *(uint2*)&sA[edge][p * 16 + 4 * i] = pk.u;
    }
#pragma unroll
    for (int i = 0; i < 4; i++) {
      float4 v = h4[c * 16 + p * 4 + i];
      union { _Float16 f[4]; uint2 u; } pk;
      pk.f[0] = (_Float16)v.x; pk.f[1] = (_Float16)v.y;
      pk.f[2] = (_Float16)v.z; pk.f[3] = (_Float16)v.w;
      *(uint2*)&sA[edge][64 + p * 16 + 4 * i] = pk.u;
    }
    // zero pad k in [136, 168): 8 f16 per thread
    {
      uint4 z = {0, 0, 0, 0};
      *(uint4*)&sA[edge][136 + 8 * p] = z;
    }
    if (p == 0) {
      float cd0 = coord[r * 3 + 0] - coord[c * 3 + 0];
      float cd1 = coord[r * 3 + 1] - coord[c * 3 + 1];
      float cd2 = coord[r * 3 + 2] - coord[c * 3 + 2];
      float vd0 = vel[r * 3 + 0] - vel[c * 3 + 0];
      float vd1 = vel[r * 3 + 1] - vel[c * 3 + 1];
      float vd2 = vel[r * 3 + 2] - vel[c * 3 + 2];
      float fx = sqrtf(cd0 * cd0 + cd1 * cd1 + cd2 * cd2);
      float fv = sqrtf(vd0 * vd0 + vd1 * vd1 + vd2 * vd2);
      float fxv = (cd0 * vd0 + cd1 * vd1 + cd2 * vd2) / (fx * fv);
      sA[edge][128] = (_Float16)fx;
      sA[edge][129] = (_Float16)fv;
      sA[edge][130] = (_Float16)fxv;
      sA[edge][131] = (_Float16)0.f; sA[edge][132] = (_Float16)0.f;
      sA[edge][133] = (_Float16)0.f; sA[edge][134] = (_Float16)0.f;
      sA[edge][135] = (_Float16)0.f;
      sCD[edge] = make_float4(cd0, cd1, cd2, 0.0f);
    }
  }
  __syncthreads();

  const int lane = t & 63, w = t >> 6;
  const int g = lane >> 4, q = lane & 15;
  const int erow = w * 16 + q;

  // ---------------- layer 1: K=160 (5 ksteps), 4 out-tiles ----------------
  f32x4 acc[4] = {};
#pragma unroll
  for (int ks = 0; ks < 5; ks++) {
    int kb = ks * 32 + g * 8;
    f16x8 bfrag = *(const f16x8*)&sA[erow][kb];
#pragma unroll
    for (int n = 0; n < 4; n++) {
      f16x8 afrag = *(const f16x8*)&w1t[(n * 16 + q) * WR1 + kb];
      acc[n] = __builtin_amdgcn_mfma_f32_16x16x32_f16(afrag, bfrag, acc[n], 0, 0, 0);
    }
  }
  // bias + relu -> restage m1^T into sM[w] as [edge][out] f16
#pragma unroll
  for (int n = 0; n < 4; n++) {
    float4 b = *(const float4*)&e_b1[n * 16 + g * 4];
    float v0 = fmaxf(acc[n][0] + b.x, 0.f);
    float v1 = fmaxf(acc[n][1] + b.y, 0.f);
    float v2 = fmaxf(acc[n][2] + b.z, 0.f);
    float v3 = fmaxf(acc[n][3] + b.w, 0.f);
    union { _Float16 f[2]; unsigned u; } p01, p23;
    p01.f[0] = (_Float16)v0; p01.f[1] = (_Float16)v1;
    p23.f[0] = (_Float16)v2; p23.f[1] = (_Float16)v3;
    *(unsigned*)&sM[w][q][n * 16 + g * 4]     = p01.u;
    *(unsigned*)&sM[w][q][n * 16 + g * 4 + 2] = p23.u;
  }
  __syncthreads();

  // ---------------- layer 2: K=64 (2 ksteps) ----------------
  f32x4 acc2[4] = {};
#pragma unroll
  for (int ks = 0; ks < 2; ks++) {
    int kb = ks * 32 + g * 8;
    f16x8 bfrag = *(const f16x8*)&sM[w][q][kb];
#pragma unroll
    for (int n = 0; n < 4; n++) {
      f16x8 afrag = *(const f16x8*)&w2t[(n * 16 + q) * WR2 + kb];
      acc2[n] = __builtin_amdgcn_mfma_f32_16x16x32_f16(afrag, bfrag, acc2[n], 0, 0, 0);
    }
  }
  __syncthreads();  // all reads of sM (m1) done before overwrite
  // bias + relu -> m2 (the message) -> sM (overwrite)
#pragma unroll
  for (int n = 0; n < 4; n++) {
    float4 b = *(const float4*)&e_b2[n * 16 + g * 4];
    float v0 = fmaxf(acc2[n][0] + b.x, 0.f);
    float v1 = fmaxf(acc2[n][1] + b.y, 0.f);
    float v2 = fmaxf(acc2[n][2] + b.z, 0.f);
    float v3 = fmaxf(acc2[n][3] + b.w, 0.f);
    union { _Float16 f[2]; unsigned u; } p01, p23;
    p01.f[0] = (_Float16)v0; p01.f[1] = (_Float16)v1;
    p23.f[0] = (_Float16)v2; p23.f[1] = (_Float16)v3;
    *(unsigned*)&sM[w][q][n * 16 + g * 4]     = p01.u;
    *(unsigned*)&sM[w][q][n * 16 + g * 4 + 2] = p23.u;
  }
  __syncthreads();

  // ---------------- coalesced mbuf store (16 edges x 128B) ----------------
  {
    int edge = lane >> 2, qq = lane & 3;
    f16x8 v0 = *(const f16x8*)&sM[w][edge][qq * 16];
    f16x8 v1 = *(const f16x8*)&sM[w][edge][qq * 16 + 8];
    size_t rowb = (size_t)(e_base + w * 16 + edge) * kHid;
    *(f16x8*)&mbuf[rowb + qq * 16]     = v0;
    *(f16x8*)&mbuf[rowb + qq * 16 + 8] = v1;
  }

  // ---------------- coord head: K=64, then dot with c_w ----------------
  f32x4 acc3[4] = {};
#pragma unroll
  for (int ks = 0; ks < 2; ks++) {
    int kb = ks * 32 + g * 8;
    f16x8 bfrag = *(const f16x8*)&sM[w][q][kb];
#pragma unroll
    for (int n = 0; n < 4; n++) {
      f16x8 afrag = *(const f16x8*)&w3t[(n * 16 + q) * WR2 + kb];
      acc3[n] = __builtin_amdgcn_mfma_f32_16x16x32_f16(afrag, bfrag, acc3[n], 0, 0, 0);
    }
  }
  float s = 0.0f;
#pragma unroll
  for (int n = 0; n < 4; n++) {
    float4 b  = *(const float4*)&c_b1[n * 16 + g * 4];
    float4 cw = *(const float4*)&c_w[n * 16 + g * 4];
    s += fmaxf(acc3[n][0] + b.x, 0.f) * cw.x;
    s += fmaxf(acc3[n][1] + b.y, 0.f) * cw.y;
    s += fmaxf(acc3[n][2] + b.z, 0.f) * cw.z;
    s += fmaxf(acc3[n][3] + b.w, 0.f) * cw.w;
  }
  s += __shfl_xor(s, 16);
  s += __shfl_xor(s, 32);  // all lanes: full s for edge lane&15

  if (lane < 16) {
    float4 cd = sCD[w * 16 + lane];
    float t0 = fminf(fmaxf(cd.x * s, -100.0f), 100.0f);
    float t1 = fminf(fmaxf(cd.y * s, -100.0f), 100.0f);
    float t2 = fminf(fmaxf(cd.z * s, -100.0f), 100.0f);
    reinterpret_cast<float4*>(transbuf)[e_base + w * 16 + lane] =
        make_float4(t0, t1, t2, 0.0f);
  }
}

// ---------------------------------------------------------------------------
// Gather: one wave per node; lane j sums feature j over CSR edge list.
// ---------------------------------------------------------------------------
__global__ __launch_bounds__(256) void egnn_gather_kernel(
    const _Float16* __restrict__ mbuf, const float* __restrict__ transbuf,
    const int* __restrict__ rowstart, const int* __restrict__ eids,
    float* __restrict__ agg, float* __restrict__ coord_out)
{
  int node = blockIdx.x * 4 + (threadIdx.x >> 6);
  if (node >= kNodes) return;
  int lane = threadIdx.x & 63;
  int start = rowstart[node];
  int end = rowstart[node + 1];

  float a = 0.0f;
#pragma unroll 4
  for (int k = start; k < end; k++) {
    int eid = eids[k];
    a += (float)mbuf[(size_t)eid * kHid + lane];
  }
  agg[(size_t)node * kHid + lane] = a;

  float t0 = 0.0f, t1 = 0.0f, t2 = 0.0f;
  for (int k = start + lane; k < end; k += 64) {
    int eid = eids[k];
    float4 tv = reinterpret_cast<const float4*>(transbuf)[eid];
    t0 += tv.x; t1 += tv.y; t2 += tv.z;
  }
#pragma unroll
  for (int m = 32; m >= 1; m >>= 1) {
    t0 += __shfl_xor(t0, m);
    t1 += __shfl_xor(t1, m);
    t2 += __shfl_xor(t2, m);
  }
  if (lane == 0) {
    float cc = fmaxf((float)(end - start), 1.0f);
    coord_out[(size_t)node * 3 + 0] = t0 / cc;
    coord_out[(size_t)node * 3 + 1] = t1 / cc;
    coord_out[(size_t)node * 3 + 2] = t2 / cc;
  }
}

// ---------------------------------------------------------------------------
// Node MLP (fp32 VALU): h_out = relu([h, agg] @ n_w1 + n_b1) @ n_w2 + n_b2
// ---------------------------------------------------------------------------
__device__ __forceinline__ void node_mlp(
    int i, const float* __restrict__ h, const float* __restrict__ agg,
    const float* __restrict__ n_w1, const float* __restrict__ n_b1,
    const float* __restrict__ n_w2, const float* __restrict__ n_b2,
    float* __restrict__ h_out)
{
  const float4* h4 = reinterpret_cast<const float4*>(h);
  const float4* a4 = reinterpret_cast<const float4*>(agg);

  float t1[kHid];
#pragma unroll
  for (int j = 0; j < kHid; j++) t1[j] = n_b1[j];

#pragma unroll 4
  for (int k4 = 0; k4 < 16; k4++) {
    float4 x4 = h4[i * 16 + k4];
    float xs[4] = {x4.x, x4.y, x4.z, x4.w};
#pragma unroll
    for (int u = 0; u < 4; u++) {
      float x = xs[u];
      const float* w = n_w1 + (k4 * 4 + u) * kHid;
#pragma unroll
      for (int j = 0; j < kHid; j++) t1[j] += x * w[j];
    }
  }
#pragma unroll 4
  for (int k4 = 0; k4 < 16; k4++) {
    float4 x4 = a4[i * 16 + k4];
    float xs[4] = {x4.x, x4.y, x4.z, x4.w};
#pragma unroll
    for (int u = 0; u < 4; u++) {
      float x = xs[u];
      const float* w = n_w1 + (64 + k4 * 4 + u) * kHid;
#pragma unroll
      for (int j = 0; j < kHid; j++) t1[j] += x * w[j];
    }
  }
#pragma unroll
  for (int j = 0; j < kHid; j++) t1[j] = fmaxf(t1[j], 0.0f);

  float out[kHid];
#pragma unroll
  for (int j = 0; j < kHid; j++) out[j] = n_b2[j];
#pragma unroll
  for (int k = 0; k < kHid; k++) {
    float x = t1[k];
    const float* w = n_w2 + k * kHid;
#pragma unroll
    for (int j = 0; j < kHid; j++) out[j] += x * w[j];
  }

  float4* ho4 = reinterpret_cast<float4*>(h_out);
#pragma unroll
  for (int j4 = 0; j4 < 16; j4++) {
    ho4[i * 16 + j4] = make_float4(out[j4 * 4 + 0], out[j4 * 4 + 1],
                                   out[j4 * 4 + 2], out[j4 * 4 + 3]);
  }
}

__global__ __launch_bounds__(256) void egnn_node_kernel(
    const float* __restrict__ h, const float* __restrict__ agg,
    const float* __restrict__ n_w1, const float* __restrict__ n_b1,
    const float* __restrict__ n_w2, const float* __restrict__ n_b2,
    float* __restrict__ h_out)
{
  int i = blockIdx.x * 256 + threadIdx.x;
  if (i >= kNodes) return;
  node_mlp(i, h, agg, n_w1, n_b1, n_w2, n_b2, h_out);
}

// ---------------------------------------------------------------------------
// Fallback (atomic scatter) path — correctness insurance if ws too small.
// ---------------------------------------------------------------------------
__global__ __launch_bounds__(256) void egnn_edge_atomic(
    const float* __restrict__ h, const float* __restrict__ coord,
    const float* __restrict__ vel,
    const int* __restrict__ rows, const int* __restrict__ cols,
    const float* __restrict__ e_w1, const float* __restrict__ e_b1,
    const float* __restrict__ e_w2, const float* __restrict__ e_b2,
    const float* __restrict__ c_w1, const float* __restrict__ c_b1,
    const float* __restrict__ c_w,
    float* __restrict__ agg, float* __restrict__ seg, float* __restrict__ cnt)
{
  int e = blockIdx.x * 256 + threadIdx.x;
  if (e >= kEdges) return;
  int r = rows[e];
  int c = cols[e];
  float cd0 = coord[r * 3 + 0] - coord[c * 3 + 0];
  float cd1 = coord[r * 3 + 1] - coord[c * 3 + 1];
  float cd2 = coord[r * 3 + 2] - coord[c * 3 + 2];
  float vd0 = vel[r * 3 + 0] - vel[c * 3 + 0];
  float vd1 = vel[r * 3 + 1] - vel[c * 3 + 1];
  float vd2 = vel[r * 3 + 2] - vel[c * 3 + 2];
  float fx = sqrtf(cd0 * cd0 + cd1 * cd1 + cd2 * cd2);
  float fv = sqrtf(vd0 * vd0 + vd1 * vd1 + vd2 * vd2);
  float fxv = (cd0 * vd0 + cd1 * vd1 + cd2 * vd2) / (fx * fv);
  const float4* h4 = reinterpret_cast<const float4*>(h);
  float m1[kHid];
#pragma unroll
  for (int j = 0; j < kHid; j++) m1[j] = e_b1[j];
#pragma unroll 4
  for (int k4 = 0; k4 < 16; k4++) {
    float4 x4 = h4[r * 16 + k4];
    float xs[4] = {x4.x, x4.y, x4.z, x4.w};
#pragma unroll
    for (int u = 0; u < 4; u++) {
      float x = xs[u];
      const float* w = e_w1 + (k4 * 4 + u) * kHid;
#pragma unroll
      for (int j = 0; j < kHid; j++) m1[j] += x * w[j];
    }
  }
#pragma unroll 4
  for (int k4 = 0; k4 < 16; k4++) {
    float4 x4 = h4[c * 16 + k4];
    float xs[4] = {x4.x, x4.y, x4.z, x4.w};
#pragma unroll
    for (int u = 0; u < 4; u++) {
      float x = xs[u];
      const float* w = e_w1 + (64 + k4 * 4 + u) * kHid;
#pragma unroll
      for (int j = 0; j < kHid; j++) m1[j] += x * w[j];
    }
  }
  {
    float rad[3] = {fx, fv, fxv};
#pragma unroll
    for (int u = 0; u < 3; u++) {
      float x = rad[u];
      const float* w = e_w1 + (128 + u) * kHid;
#pragma unroll
      for (int j = 0; j < kHid; j++) m1[j] += x * w[j];
    }
  }
#pragma unroll
  for (int j = 0; j < kHid; j++) m1[j] = fmaxf(m1[j], 0.0f);
  float m2[kHid];
#pragma unroll
  for (int j = 0; j < kHid; j++) m2[j] = e_b2[j];
#pragma unroll
  for (int k = 0; k < kHid; k++) {
    float x = m1[k];
    const float* w = e_w2 + k * kHid;
#pragma unroll
    for (int j = 0; j < kHid; j++) m2[j] += x * w[j];
  }
#pragma unroll
  for (int j = 0; j < kHid; j++) m2[j] = fmaxf(m2[j], 0.0f);
  float s = 0.0f;
  {
    float tt[kHid];
#pragma unroll
    for (int j = 0; j < kHid; j++) tt[j] = c_b1[j];
#pragma unroll
    for (int k = 0; k < kHid; k++) {
      float x = m2[k];
      const float* w = c_w1 + k * kHid;
#pragma unroll
      for (int j = 0; j < kHid; j++) tt[j] += x * w[j];
    }
#pragma unroll
    for (int j = 0; j < kHid; j++) s += fmaxf(tt[j], 0.0f) * c_w[j];
  }
  float t0 = fminf(fmaxf(cd0 * s, -100.0f), 100.0f);
  float t1 = fminf(fmaxf(cd1 * s, -100.0f), 100.0f);
  float t2 = fminf(fmaxf(cd2 * s, -100.0f), 100.0f);
  atomicAdd(&seg[r * 3 + 0], t0);
  atomicAdd(&seg[r * 3 + 1], t1);
  atomicAdd(&seg[r * 3 + 2], t2);
  atomicAdd(&cnt[r], 1.0f);
#pragma unroll
  for (int j = 0; j < kHid; j++) atomicAdd(&agg[r * kHid + j], m2[j]);
}

__global__ __launch_bounds__(256) void egnn_node_fallback_kernel(
    const float* __restrict__ h, const float* __restrict__ agg,
    const float* __restrict__ seg, const float* __restrict__ cnt,
    const float* __restrict__ n_w1, const float* __restrict__ n_b1,
    const float* __restrict__ n_w2, const float* __restrict__ n_b2,
    float* __restrict__ h_out, float* __restrict__ coord_out)
{
  int i = blockIdx.x * 256 + threadIdx.x;
  if (i >= kNodes) return;
  node_mlp(i, h, agg, n_w1, n_b1, n_w2, n_b2, h_out);
  float cc = fmaxf(cnt[i], 1.0f);
  coord_out[i * 3 + 0] = seg[i * 3 + 0] / cc;
  coord_out[i * 3 + 1] = seg[i * 3 + 1] / cc;
  coord_out[i * 3 + 2] = seg[i * 3 + 2] / cc;
}

extern "C" void kernel_launch(void* const* d_in, const int* in_sizes, int n_in,
                              void* d_out, int out_size, void* d_ws, size_t ws_size,
                              hipStream_t stream) {
  const float* h     = (const float*)d_in[0];
  const float* coord = (const float*)d_in[1];
  const float* vel   = (const float*)d_in[2];
  const int* edge_index = (const int*)d_in[3];
  const float* e_w1 = (const float*)d_in[4];
  const float* e_b1 = (const float*)d_in[5];
  const float* e_w2 = (const float*)d_in[6];
  const float* e_b2 = (const float*)d_in[7];
  const float* n_w1 = (const float*)d_in[8];
  const float* n_b1 = (const float*)d_in[9];
  const float* n_w2 = (const float*)d_in[10];
  const float* n_b2 = (const float*)d_in[11];
  const float* c_w1 = (const float*)d_in[12];
  const float* c_b1 = (const float*)d_in[13];
  const float* c_w  = (const float*)d_in[14];

  const int* rows = edge_index;
  const int* cols = edge_index + kEdges;

  float* h_out = (float*)d_out;
  float* coord_out = h_out + (size_t)kNodes * kNF;

  // ---- workspace layout (bytes) ----
  const size_t off_mbuf   = 0;                                      // E*64*2
  const size_t off_trans  = off_mbuf   + (size_t)kEdges * kHid * 2; // E*16
  const size_t off_agg    = off_trans  + (size_t)kEdges * 16;       // N*64*4
  const size_t off_eids   = off_agg    + (size_t)kNodes * kHid * 4; // E*4
  const size_t off_hist   = off_eids   + (size_t)kEdges * 4;        // N*4
  const size_t off_cursor = off_hist   + (size_t)kNodes * 4;        // N*4
  const size_t off_rowst  = off_cursor + (size_t)kNodes * 4;        // (N+1)*4 -> pad
  const size_t off_w1t    = off_rowst  + 200064;                    // 64*168*2
  const size_t off_w2t    = off_w1t    + 64 * WR1 * 2;              // 64*72*2
  const size_t off_w3t    = off_w2t    + 64 * WR2 * 2;              // 64*72*2
  const size_t off_bsum   = off_w3t    + 64 * WR2 * 2;
  const size_t off_boff   = off_bsum   + 256;
  const size_t need       = off_boff   + 256;

  char* ws = (char*)d_ws;

  if (ws_size >= need) {
    _Float16* mbuf    = (_Float16*)(ws + off_mbuf);
    float* transbuf   = (float*)(ws + off_trans);
    float* agg        = (float*)(ws + off_agg);
    int* eids         = (int*)(ws + off_eids);
    int* hist         = (int*)(ws + off_hist);
    int* cursor       = (int*)(ws + off_cursor);
    int* rowstart     = (int*)(ws + off_rowst);
    _Float16* w1t     = (_Float16*)(ws + off_w1t);
    _Float16* w2t     = (_Float16*)(ws + off_w2t);
    _Float16* w3t     = (_Float16*)(ws + off_w3t);
    int* bsum         = (int*)(ws + off_bsum);
    int* boff         = (int*)(ws + off_boff);

    hipMemsetAsync(ws + off_hist, 0, (size_t)kNodes * 4 * 2, stream);  // hist+cursor

    prep_weights<<<42, 256, 0, stream>>>(e_w1, e_w2, c_w1, w1t, w2t, w3t);

    hist_kernel<<<(kEdges + 255) / 256, 256, 0, stream>>>(rows, hist);
    const int nb = (kNodes + 1023) / 1024;  // 49
    scan1<<<nb, 1024, 0, stream>>>(hist, rowstart, bsum);
    scan2<<<1, 64, 0, stream>>>(bsum, boff, rowstart);
    scan3<<<nb, 1024, 0, stream>>>(rowstart, boff);
    scatter_kernel<<<(kEdges + 255) / 256, 256, 0, stream>>>(rows, rowstart, cursor, eids);

    egnn_edge_mfma<<<kEdges / 64, 256, 0, stream>>>(
        h, coord, vel, rows, cols, w1t, w2t, w3t,
        e_b1, e_b2, c_b1, c_w, mbuf, transbuf);

    egnn_gather_kernel<<<(kNodes + 3) / 4, 256, 0, stream>>>(
        mbuf, transbuf, rowstart, eids, agg, coord_out);

    egnn_node_kernel<<<(kNodes + 255) / 256, 256, 0, stream>>>(
        h, agg, n_w1, n_b1, n_w2, n_b2, h_out);
  } else {
    float* agg = (float*)d_ws;
    float* seg = agg + (size_t)kNodes * kHid;
    float* cnt = seg + (size_t)kNodes * 3;
    hipMemsetAsync(d_ws, 0, (size_t)kNodes * (kHid + 4) * sizeof(float), stream);

    egnn_edge_atomic<<<(kEdges + 255) / 256, 256, 0, stream>>>(
        h, coord, vel, rows, cols, e_w1, e_b1, e_w2, e_b2, c_w1, c_b1, c_w,
        agg, seg, cnt);

    egnn_node_fallback_kernel<<<(kNodes + 255) / 256, 256, 0, stream>>>(
        h, agg, seg, cnt, n_w1, n_b1, n_w2, n_b2, h_out, coord_out);
  }
}

// Round 4
// 292.647 us; speedup vs baseline: 10.8867x; 1.3274x over previous
//
#include <hip/hip_runtime.h>

constexpr int kNodes = 50000;
constexpr int kEdges = 800000;
constexpr int kNF  = 64;
constexpr int kHid = 64;

constexpr int LDA   = 168;  // sA row stride f16 (16B-multiple: 336B)
constexpr int WR1   = 168;  // w1t row stride
constexpr int WR2   = 72;   // w2t/w3t/nw2t/sM row stride
constexpr int WRN   = 136;  // nw1t / sN row stride (K=128 pad to 136)

typedef _Float16 f16x8 __attribute__((ext_vector_type(8)));
typedef float    f32x4 __attribute__((ext_vector_type(4)));

// ---------------------------------------------------------------------------
// Weight prep: transpose + f16 convert, zero-padded K.
// ---------------------------------------------------------------------------
__global__ __launch_bounds__(256) void prep_weights(
    const float* __restrict__ e_w1, const float* __restrict__ e_w2,
    const float* __restrict__ c_w1, const float* __restrict__ n_w1,
    const float* __restrict__ n_w2,
    _Float16* __restrict__ w1t, _Float16* __restrict__ w2t,
    _Float16* __restrict__ w3t, _Float16* __restrict__ nw1t,
    _Float16* __restrict__ nw2t)
{
  int t = blockIdx.x * 256 + threadIdx.x;
  int total = gridDim.x * 256;
  for (int idx = t; idx < 64 * WR1; idx += total) {
    int j = idx / WR1, k = idx % WR1;
    w1t[idx] = (k < 131) ? (_Float16)e_w1[k * 64 + j] : (_Float16)0.f;
  }
  for (int idx = t; idx < 64 * WR2; idx += total) {
    int j = idx / WR2, k = idx % WR2;
    w2t[idx]  = (k < 64) ? (_Float16)e_w2[k * 64 + j] : (_Float16)0.f;
    w3t[idx]  = (k < 64) ? (_Float16)c_w1[k * 64 + j] : (_Float16)0.f;
    nw2t[idx] = (k < 64) ? (_Float16)n_w2[k * 64 + j] : (_Float16)0.f;
  }
  for (int idx = t; idx < 64 * WRN; idx += total) {
    int j = idx / WRN, k = idx % WRN;
    nw1t[idx] = (k < 128) ? (_Float16)n_w1[k * 64 + j] : (_Float16)0.f;
  }
}

// h -> f16 table + nodein[:,0:64]; pack coord+vel as float4 pairs.
__global__ __launch_bounds__(256) void prep_nodes(
    const float* __restrict__ h, const float* __restrict__ coord,
    const float* __restrict__ vel,
    _Float16* __restrict__ h16, _Float16* __restrict__ nodein,
    float4* __restrict__ cv)
{
  int tid = blockIdx.x * 256 + threadIdx.x;
  if (tid < kNodes * 64) {
    int n = tid >> 6, j = tid & 63;
    _Float16 v = (_Float16)h[tid];
    h16[tid] = v;
    nodein[(size_t)n * 128 + j] = v;
  }
  if (tid < kNodes) {
    cv[2 * tid]     = make_float4(coord[3 * tid], coord[3 * tid + 1], coord[3 * tid + 2], 0.f);
    cv[2 * tid + 1] = make_float4(vel[3 * tid],   vel[3 * tid + 1],   vel[3 * tid + 2],   0.f);
  }
}

// ---------------------------------------------------------------------------
// CSR build: histogram -> 3-stage scan -> cursor scatter (writes srows/scols)
// ---------------------------------------------------------------------------
__global__ __launch_bounds__(256) void hist_kernel(const int* __restrict__ rows,
                                                   int* __restrict__ hist) {
  int e = blockIdx.x * 256 + threadIdx.x;
  if (e < kEdges) atomicAdd(&hist[rows[e]], 1);
}

__global__ __launch_bounds__(1024) void scan1(const int* __restrict__ hist,
                                              int* __restrict__ rowstart,
                                              int* __restrict__ bsum) {
  int t = threadIdx.x;
  int i = blockIdx.x * 1024 + t;
  int lane = t & 63, wv = t >> 6;
  int v = (i < kNodes) ? hist[i] : 0;
  int acc = v;
#pragma unroll
  for (int off = 1; off < 64; off <<= 1) {
    int u = __shfl_up(acc, off);
    if (lane >= off) acc += u;
  }
  __shared__ int wsum[16];
  if (lane == 63) wsum[wv] = acc;
  __syncthreads();
  if (t < 16) {
    int ws = wsum[t];
#pragma unroll
    for (int off = 1; off < 16; off <<= 1) {
      int u = __shfl_up(ws, off);
      if (lane >= off) ws += u;
    }
    wsum[t] = ws;
  }
  __syncthreads();
  int woff = (wv == 0) ? 0 : wsum[wv - 1];
  if (i < kNodes) rowstart[i] = woff + acc - v;
  if (t == 1023) bsum[blockIdx.x] = wsum[15];
}

__global__ void scan2(const int* __restrict__ bsum, int* __restrict__ boff,
                      int* __restrict__ rowstart) {
  int lane = threadIdx.x;
  const int nb = (kNodes + 1023) / 1024;
  int v = (lane < nb) ? bsum[lane] : 0;
  int acc = v;
#pragma unroll
  for (int off = 1; off < 64; off <<= 1) {
    int u = __shfl_up(acc, off);
    if (lane >= off) acc += u;
  }
  if (lane < nb) boff[lane] = acc - v;
  if (lane == nb - 1) rowstart[kNodes] = acc;
}

__global__ __launch_bounds__(1024) void scan3(int* __restrict__ rowstart,
                                              const int* __restrict__ boff) {
  int i = blockIdx.x * 1024 + threadIdx.x;
  if (i < kNodes) rowstart[i] += boff[blockIdx.x];
}

__global__ __launch_bounds__(256) void scatter_kernel(
    const int* __restrict__ rows, const int* __restrict__ cols,
    const int* __restrict__ rowstart, int* __restrict__ cursor,
    int* __restrict__ srows, int* __restrict__ scols) {
  int e = blockIdx.x * 256 + threadIdx.x;
  if (e >= kEdges) return;
  int r = rows[e];
  int p = atomicAdd(&cursor[r], 1);
  int dst = rowstart[r] + p;
  srows[dst] = r;
  scols[dst] = cols[e];
}

// ---------------------------------------------------------------------------
// MFMA edge kernel over CSR-sorted edges. Block = 64 edges, 4 waves.
// Transposed layers D = W^T . X^T; edge = lane&15 throughout.
// ---------------------------------------------------------------------------
__global__ __launch_bounds__(256) void egnn_edge_mfma(
    const _Float16* __restrict__ h16, const float4* __restrict__ cv,
    const int* __restrict__ srows, const int* __restrict__ scols,
    const _Float16* __restrict__ w1t, const _Float16* __restrict__ w2t,
    const _Float16* __restrict__ w3t,
    const float* __restrict__ e_b1, const float* __restrict__ e_b2,
    const float* __restrict__ c_b1, const float* __restrict__ c_w,
    _Float16* __restrict__ mbuf, float* __restrict__ transbuf)
{
  __shared__ _Float16 sA[64][LDA];
  __shared__ _Float16 sM[4][16][WR2];
  __shared__ float4 sCD[64];

  const int t = threadIdx.x;
  const int e_base = blockIdx.x * 64;

  // ---- stage: gather h16[r], h16[c], radial -> sA ----
  {
    int edge = t >> 2, p = t & 3;
    int pos = e_base + edge;
    int r = srows[pos], c = scols[pos];
    const uint4* hr = (const uint4*)(h16 + (size_t)r * 64);
    const uint4* hc = (const uint4*)(h16 + (size_t)c * 64);
    *(uint4*)&sA[edge][p * 16]          = hr[p * 2];
    *(uint4*)&sA[edge][p * 16 + 8]      = hr[p * 2 + 1];
    *(uint4*)&sA[edge][64 + p * 16]     = hc[p * 2];
    *(uint4*)&sA[edge][64 + p * 16 + 8] = hc[p * 2 + 1];
    uint4 z = {0, 0, 0, 0};
    *(uint4*)&sA[edge][136 + 8 * p] = z;
    if (p == 0) {
      float4 cr = cv[2 * r], vr = cv[2 * r + 1];
      float4 cc = cv[2 * c], vc = cv[2 * c + 1];
      float cd0 = cr.x - cc.x, cd1 = cr.y - cc.y, cd2 = cr.z - cc.z;
      float vd0 = vr.x - vc.x, vd1 = vr.y - vc.y, vd2 = vr.z - vc.z;
      float fx = sqrtf(cd0 * cd0 + cd1 * cd1 + cd2 * cd2);
      float fv = sqrtf(vd0 * vd0 + vd1 * vd1 + vd2 * vd2);
      float fxv = (cd0 * vd0 + cd1 * vd1 + cd2 * vd2) / (fx * fv);
      sA[edge][128] = (_Float16)fx;
      sA[edge][129] = (_Float16)fv;
      sA[edge][130] = (_Float16)fxv;
      sA[edge][131] = (_Float16)0.f; sA[edge][132] = (_Float16)0.f;
      sA[edge][133] = (_Float16)0.f; sA[edge][134] = (_Float16)0.f;
      sA[edge][135] = (_Float16)0.f;
      sCD[edge] = make_float4(cd0, cd1, cd2, 0.0f);
    }
  }
  __syncthreads();

  const int lane = t & 63, w = t >> 6;
  const int g = lane >> 4, q = lane & 15;
  const int erow = w * 16 + q;

  // ---- layer 1: K=160 ----
  f32x4 acc[4] = {};
#pragma unroll
  for (int ks = 0; ks < 5; ks++) {
    int kb = ks * 32 + g * 8;
    f16x8 bfrag = *(const f16x8*)&sA[erow][kb];
#pragma unroll
    for (int n = 0; n < 4; n++) {
      f16x8 afrag = *(const f16x8*)&w1t[(n * 16 + q) * WR1 + kb];
      acc[n] = __builtin_amdgcn_mfma_f32_16x16x32_f16(afrag, bfrag, acc[n], 0, 0, 0);
    }
  }
#pragma unroll
  for (int n = 0; n < 4; n++) {
    float4 b = *(const float4*)&e_b1[n * 16 + g * 4];
    float v0 = fmaxf(acc[n][0] + b.x, 0.f);
    float v1 = fmaxf(acc[n][1] + b.y, 0.f);
    float v2 = fmaxf(acc[n][2] + b.z, 0.f);
    float v3 = fmaxf(acc[n][3] + b.w, 0.f);
    union { _Float16 f[2]; unsigned u; } p01, p23;
    p01.f[0] = (_Float16)v0; p01.f[1] = (_Float16)v1;
    p23.f[0] = (_Float16)v2; p23.f[1] = (_Float16)v3;
    *(unsigned*)&sM[w][q][n * 16 + g * 4]     = p01.u;
    *(unsigned*)&sM[w][q][n * 16 + g * 4 + 2] = p23.u;
  }
  __syncthreads();

  // ---- layer 2: K=64 ----
  f32x4 acc2[4] = {};
#pragma unroll
  for (int ks = 0; ks < 2; ks++) {
    int kb = ks * 32 + g * 8;
    f16x8 bfrag = *(const f16x8*)&sM[w][q][kb];
#pragma unroll
    for (int n = 0; n < 4; n++) {
      f16x8 afrag = *(const f16x8*)&w2t[(n * 16 + q) * WR2 + kb];
      acc2[n] = __builtin_amdgcn_mfma_f32_16x16x32_f16(afrag, bfrag, acc2[n], 0, 0, 0);
    }
  }
  __syncthreads();
#pragma unroll
  for (int n = 0; n < 4; n++) {
    float4 b = *(const float4*)&e_b2[n * 16 + g * 4];
    float v0 = fmaxf(acc2[n][0] + b.x, 0.f);
    float v1 = fmaxf(acc2[n][1] + b.y, 0.f);
    float v2 = fmaxf(acc2[n][2] + b.z, 0.f);
    float v3 = fmaxf(acc2[n][3] + b.w, 0.f);
    union { _Float16 f[2]; unsigned u; } p01, p23;
    p01.f[0] = (_Float16)v0; p01.f[1] = (_Float16)v1;
    p23.f[0] = (_Float16)v2; p23.f[1] = (_Float16)v3;
    *(unsigned*)&sM[w][q][n * 16 + g * 4]     = p01.u;
    *(unsigned*)&sM[w][q][n * 16 + g * 4 + 2] = p23.u;
  }
  __syncthreads();

  // ---- coalesced mbuf store (CSR order) ----
  {
    int edge = lane >> 2, qq = lane & 3;
    f16x8 v0 = *(const f16x8*)&sM[w][edge][qq * 16];
    f16x8 v1 = *(const f16x8*)&sM[w][edge][qq * 16 + 8];
    size_t rowb = (size_t)(e_base + w * 16 + edge) * kHid;
    *(f16x8*)&mbuf[rowb + qq * 16]     = v0;
    *(f16x8*)&mbuf[rowb + qq * 16 + 8] = v1;
  }

  // ---- coord head ----
  f32x4 acc3[4] = {};
#pragma unroll
  for (int ks = 0; ks < 2; ks++) {
    int kb = ks * 32 + g * 8;
    f16x8 bfrag = *(const f16x8*)&sM[w][q][kb];
#pragma unroll
    for (int n = 0; n < 4; n++) {
      f16x8 afrag = *(const f16x8*)&w3t[(n * 16 + q) * WR2 + kb];
      acc3[n] = __builtin_amdgcn_mfma_f32_16x16x32_f16(afrag, bfrag, acc3[n], 0, 0, 0);
    }
  }
  float s = 0.0f;
#pragma unroll
  for (int n = 0; n < 4; n++) {
    float4 b  = *(const float4*)&c_b1[n * 16 + g * 4];
    float4 cw = *(const float4*)&c_w[n * 16 + g * 4];
    s += fmaxf(acc3[n][0] + b.x, 0.f) * cw.x;
    s += fmaxf(acc3[n][1] + b.y, 0.f) * cw.y;
    s += fmaxf(acc3[n][2] + b.z, 0.f) * cw.z;
    s += fmaxf(acc3[n][3] + b.w, 0.f) * cw.w;
  }
  s += __shfl_xor(s, 16);
  s += __shfl_xor(s, 32);

  if (lane < 16) {
    float4 cd = sCD[w * 16 + lane];
    float t0 = fminf(fmaxf(cd.x * s, -100.0f), 100.0f);
    float t1 = fminf(fmaxf(cd.y * s, -100.0f), 100.0f);
    float t2 = fminf(fmaxf(cd.z * s, -100.0f), 100.0f);
    reinterpret_cast<float4*>(transbuf)[e_base + w * 16 + lane] =
        make_float4(t0, t1, t2, 0.0f);
  }
}

// ---------------------------------------------------------------------------
// Gather: wave per node, streaming contiguous CSR rows.
// Lane layout: rg=lane>>3 (row in group of 8), fg=lane&7 (8 features each).
// ---------------------------------------------------------------------------
__global__ __launch_bounds__(256) void egnn_gather_kernel(
    const _Float16* __restrict__ mbuf, const float* __restrict__ transbuf,
    const int* __restrict__ rowstart,
    _Float16* __restrict__ nodein, float* __restrict__ coord_out)
{
  int node = blockIdx.x * 4 + (threadIdx.x >> 6);
  if (node >= kNodes) return;
  int lane = threadIdx.x & 63;
  int start = rowstart[node];
  int end = rowstart[node + 1];

  int rg = lane >> 3, fg = lane & 7;
  float acc[8] = {};
  for (int k = start; k < end; k += 8) {
    int row = k + rg;
    if (row < end) {
      f16x8 v = *(const f16x8*)&mbuf[(size_t)row * 64 + fg * 8];
#pragma unroll
      for (int u = 0; u < 8; u++) acc[u] += (float)v[u];
    }
  }
#pragma unroll
  for (int off = 8; off < 64; off <<= 1) {
#pragma unroll
    for (int u = 0; u < 8; u++) acc[u] += __shfl_down(acc[u], off);
  }
  if (lane < 8) {
    union { _Float16 f[8]; uint4 u4; } pk;
#pragma unroll
    for (int u = 0; u < 8; u++) pk.f[u] = (_Float16)acc[u];
    *(uint4*)&nodein[(size_t)node * 128 + 64 + lane * 8] = pk.u4;
  }

  float t0 = 0.0f, t1 = 0.0f, t2 = 0.0f;
  for (int k = start + lane; k < end; k += 64) {
    float4 tv = reinterpret_cast<const float4*>(transbuf)[k];
    t0 += tv.x; t1 += tv.y; t2 += tv.z;
  }
#pragma unroll
  for (int m = 32; m >= 1; m >>= 1) {
    t0 += __shfl_xor(t0, m);
    t1 += __shfl_xor(t1, m);
    t2 += __shfl_xor(t2, m);
  }
  if (lane == 0) {
    float cc = fmaxf((float)(end - start), 1.0f);
    coord_out[(size_t)node * 3 + 0] = t0 / cc;
    coord_out[(size_t)node * 3 + 1] = t1 / cc;
    coord_out[(size_t)node * 3 + 2] = t2 / cc;
  }
}

// ---------------------------------------------------------------------------
// Node MFMA kernel: block = 64 nodes, 4 waves. Same transposed-layer scheme.
// ---------------------------------------------------------------------------
__global__ __launch_bounds__(256) void egnn_node_mfma(
    const _Float16* __restrict__ nodein,
    const _Float16* __restrict__ nw1t, const _Float16* __restrict__ nw2t,
    const float* __restrict__ n_b1, const float* __restrict__ n_b2,
    float* __restrict__ h_out)
{
  __shared__ _Float16 sN[64][WRN];
  __shared__ _Float16 sM[4][16][WR2];
  __shared__ float sO[4][16][68];

  const int t = threadIdx.x;
  const int nb = blockIdx.x * 64;

  {
    int nl = t >> 2, p = t & 3;
    int node = nb + nl;
    uint4 z = {0, 0, 0, 0};
    uint4 v0 = z, v1 = z, v2 = z, v3 = z;
    if (node < kNodes) {
      const uint4* src = (const uint4*)(nodein + (size_t)node * 128);
      v0 = src[p * 4 + 0]; v1 = src[p * 4 + 1];
      v2 = src[p * 4 + 2]; v3 = src[p * 4 + 3];
    }
    *(uint4*)&sN[nl][p * 32 + 0]  = v0;
    *(uint4*)&sN[nl][p * 32 + 8]  = v1;
    *(uint4*)&sN[nl][p * 32 + 16] = v2;
    *(uint4*)&sN[nl][p * 32 + 24] = v3;
    if (p == 0) *(uint4*)&sN[nl][128] = z;
  }
  __syncthreads();

  const int lane = t & 63, w = t >> 6;
  const int g = lane >> 4, q = lane & 15;
  const int nrow = w * 16 + q;

  // ---- layer 1: K=128 ----
  f32x4 acc[4] = {};
#pragma unroll
  for (int ks = 0; ks < 4; ks++) {
    int kb = ks * 32 + g * 8;
    f16x8 bfrag = *(const f16x8*)&sN[nrow][kb];
#pragma unroll
    for (int n = 0; n < 4; n++) {
      f16x8 afrag = *(const f16x8*)&nw1t[(n * 16 + q) * WRN + kb];
      acc[n] = __builtin_amdgcn_mfma_f32_16x16x32_f16(afrag, bfrag, acc[n], 0, 0, 0);
    }
  }
#pragma unroll
  for (int n = 0; n < 4; n++) {
    float4 b = *(const float4*)&n_b1[n * 16 + g * 4];
    float v0 = fmaxf(acc[n][0] + b.x, 0.f);
    float v1 = fmaxf(acc[n][1] + b.y, 0.f);
    float v2 = fmaxf(acc[n][2] + b.z, 0.f);
    float v3 = fmaxf(acc[n][3] + b.w, 0.f);
    union { _Float16 f[2]; unsigned u; } p01, p23;
    p01.f[0] = (_Float16)v0; p01.f[1] = (_Float16)v1;
    p23.f[0] = (_Float16)v2; p23.f[1] = (_Float16)v3;
    *(unsigned*)&sM[w][q][n * 16 + g * 4]     = p01.u;
    *(unsigned*)&sM[w][q][n * 16 + g * 4 + 2] = p23.u;
  }
  __syncthreads();

  // ---- layer 2: K=64, output fp32 ----
  f32x4 acc2[4] = {};
#pragma unroll
  for (int ks = 0; ks < 2; ks++) {
    int kb = ks * 32 + g * 8;
    f16x8 bfrag = *(const f16x8*)&sM[w][q][kb];
#pragma unroll
    for (int n = 0; n < 4; n++) {
      f16x8 afrag = *(const f16x8*)&nw2t[(n * 16 + q) * WR2 + kb];
      acc2[n] = __builtin_amdgcn_mfma_f32_16x16x32_f16(afrag, bfrag, acc2[n], 0, 0, 0);
    }
  }
#pragma unroll
  for (int n = 0; n < 4; n++) {
    float4 b = *(const float4*)&n_b2[n * 16 + g * 4];
    sO[w][q][n * 16 + g * 4 + 0] = acc2[n][0] + b.x;
    sO[w][q][n * 16 + g * 4 + 1] = acc2[n][1] + b.y;
    sO[w][q][n * 16 + g * 4 + 2] = acc2[n][2] + b.z;
    sO[w][q][n * 16 + g * 4 + 3] = acc2[n][3] + b.w;
  }
  __syncthreads();

  {
    int nl = lane >> 2, p = lane & 3;
    int node = nb + w * 16 + nl;
    if (node < kNodes) {
      float4* dst = (float4*)(h_out + (size_t)node * 64 + p * 16);
      dst[0] = *(float4*)&sO[w][nl][p * 16 + 0];
      dst[1] = *(float4*)&sO[w][nl][p * 16 + 4];
      dst[2] = *(float4*)&sO[w][nl][p * 16 + 8];
      dst[3] = *(float4*)&sO[w][nl][p * 16 + 12];
    }
  }
}

// ---------------------------------------------------------------------------
// Fallback (atomic) path — insurance if ws too small.
// ---------------------------------------------------------------------------
__global__ __launch_bounds__(256) void egnn_edge_atomic(
    const float* __restrict__ h, const float* __restrict__ coord,
    const float* __restrict__ vel,
    const int* __restrict__ rows, const int* __restrict__ cols,
    const float* __restrict__ e_w1, const float* __restrict__ e_b1,
    const float* __restrict__ e_w2, const float* __restrict__ e_b2,
    const float* __restrict__ c_w1, const float* __restrict__ c_b1,
    const float* __restrict__ c_w,
    float* __restrict__ agg, float* __restrict__ seg, float* __restrict__ cnt)
{
  int e = blockIdx.x * 256 + threadIdx.x;
  if (e >= kEdges) return;
  int r = rows[e];
  int c = cols[e];
  float cd0 = coord[r * 3 + 0] - coord[c * 3 + 0];
  float cd1 = coord[r * 3 + 1] - coord[c * 3 + 1];
  float cd2 = coord[r * 3 + 2] - coord[c * 3 + 2];
  float vd0 = vel[r * 3 + 0] - vel[c * 3 + 0];
  float vd1 = vel[r * 3 + 1] - vel[c * 3 + 1];
  float vd2 = vel[r * 3 + 2] - vel[c * 3 + 2];
  float fx = sqrtf(cd0 * cd0 + cd1 * cd1 + cd2 * cd2);
  float fv = sqrtf(vd0 * vd0 + vd1 * vd1 + vd2 * vd2);
  float fxv = (cd0 * vd0 + cd1 * vd1 + cd2 * vd2) / (fx * fv);
  const float4* h4 = reinterpret_cast<const float4*>(h);
  float m1[kHid];
#pragma unroll
  for (int j = 0; j < kHid; j++) m1[j] = e_b1[j];
#pragma unroll 4
  for (int k4 = 0; k4 < 16; k4++) {
    float4 x4 = h4[r * 16 + k4];
    float xs[4] = {x4.x, x4.y, x4.z, x4.w};
#pragma unroll
    for (int u = 0; u < 4; u++) {
      float x = xs[u];
      const float* w = e_w1 + (k4 * 4 + u) * kHid;
#pragma unroll
      for (int j = 0; j < kHid; j++) m1[j] += x * w[j];
    }
  }
#pragma unroll 4
  for (int k4 = 0; k4 < 16; k4++) {
    float4 x4 = h4[c * 16 + k4];
    float xs[4] = {x4.x, x4.y, x4.z, x4.w};
#pragma unroll
    for (int u = 0; u < 4; u++) {
      float x = xs[u];
      const float* w = e_w1 + (64 + k4 * 4 + u) * kHid;
#pragma unroll
      for (int j = 0; j < kHid; j++) m1[j] += x * w[j];
    }
  }
  {
    float rad[3] = {fx, fv, fxv};
#pragma unroll
    for (int u = 0; u < 3; u++) {
      float x = rad[u];
      const float* w = e_w1 + (128 + u) * kHid;
#pragma unroll
      for (int j = 0; j < kHid; j++) m1[j] += x * w[j];
    }
  }
#pragma unroll
  for (int j = 0; j < kHid; j++) m1[j] = fmaxf(m1[j], 0.0f);
  float m2[kHid];
#pragma unroll
  for (int j = 0; j < kHid; j++) m2[j] = e_b2[j];
#pragma unroll
  for (int k = 0; k < kHid; k++) {
    float x = m1[k];
    const float* w = e_w2 + k * kHid;
#pragma unroll
    for (int j = 0; j < kHid; j++) m2[j] += x * w[j];
  }
#pragma unroll
  for (int j = 0; j < kHid; j++) m2[j] = fmaxf(m2[j], 0.0f);
  float s = 0.0f;
  {
    float tt[kHid];
#pragma unroll
    for (int j = 0; j < kHid; j++) tt[j] = c_b1[j];
#pragma unroll
    for (int k = 0; k < kHid; k++) {
      float x = m2[k];
      const float* w = c_w1 + k * kHid;
#pragma unroll
      for (int j = 0; j < kHid; j++) tt[j] += x * w[j];
    }
#pragma unroll
    for (int j = 0; j < kHid; j++) s += fmaxf(tt[j], 0.0f) * c_w[j];
  }
  float t0 = fminf(fmaxf(cd0 * s, -100.0f), 100.0f);
  float t1 = fminf(fmaxf(cd1 * s, -100.0f), 100.0f);
  float t2 = fminf(fmaxf(cd2 * s, -100.0f), 100.0f);
  atomicAdd(&seg[r * 3 + 0], t0);
  atomicAdd(&seg[r * 3 + 1], t1);
  atomicAdd(&seg[r * 3 + 2], t2);
  atomicAdd(&cnt[r], 1.0f);
#pragma unroll
  for (int j = 0; j < kHid; j++) atomicAdd(&agg[r * kHid + j], m2[j]);
}

__global__ __launch_bounds__(256) void egnn_node_fallback_kernel(
    const float* __restrict__ h, const float* __restrict__ agg,
    const float* __restrict__ seg, const float* __restrict__ cnt,
    const float* __restrict__ n_w1, const float* __restrict__ n_b1,
    const float* __restrict__ n_w2, const float* __restrict__ n_b2,
    float* __restrict__ h_out, float* __restrict__ coord_out)
{
  int i = blockIdx.x * 256 + threadIdx.x;
  if (i >= kNodes) return;
  const float4* h4 = reinterpret_cast<const float4*>(h);
  const float4* a4 = reinterpret_cast<const float4*>(agg);
  float t1[kHid];
#pragma unroll
  for (int j = 0; j < kHid; j++) t1[j] = n_b1[j];
#pragma unroll 4
  for (int k4 = 0; k4 < 16; k4++) {
    float4 x4 = h4[i * 16 + k4];
    float xs[4] = {x4.x, x4.y, x4.z, x4.w};
#pragma unroll
    for (int u = 0; u < 4; u++) {
      float x = xs[u];
      const float* w = n_w1 + (k4 * 4 + u) * kHid;
#pragma unroll
      for (int j = 0; j < kHid; j++) t1[j] += x * w[j];
    }
  }
#pragma unroll 4
  for (int k4 = 0; k4 < 16; k4++) {
    float4 x4 = a4[i * 16 + k4];
    float xs[4] = {x4.x, x4.y, x4.z, x4.w};
#pragma unroll
    for (int u = 0; u < 4; u++) {
      float x = xs[u];
      const float* w = n_w1 + (64 + k4 * 4 + u) * kHid;
#pragma unroll
      for (int j = 0; j < kHid; j++) t1[j] += x * w[j];
    }
  }
#pragma unroll
  for (int j = 0; j < kHid; j++) t1[j] = fmaxf(t1[j], 0.0f);
  float out[kHid];
#pragma unroll
  for (int j = 0; j < kHid; j++) out[j] = n_b2[j];
#pragma unroll
  for (int k = 0; k < kHid; k++) {
    float x = t1[k];
    const float* w = n_w2 + k * kHid;
#pragma unroll
    for (int j = 0; j < kHid; j++) out[j] += x * w[j];
  }
  float4* ho4 = reinterpret_cast<float4*>(h_out);
#pragma unroll
  for (int j4 = 0; j4 < 16; j4++) {
    ho4[i * 16 + j4] = make_float4(out[j4 * 4 + 0], out[j4 * 4 + 1],
                                   out[j4 * 4 + 2], out[j4 * 4 + 3]);
  }
  float cc = fmaxf(cnt[i], 1.0f);
  coord_out[i * 3 + 0] = seg[i * 3 + 0] / cc;
  coord_out[i * 3 + 1] = seg[i * 3 + 1] / cc;
  coord_out[i * 3 + 2] = seg[i * 3 + 2] / cc;
}

extern "C" void kernel_launch(void* const* d_in, const int* in_sizes, int n_in,
                              void* d_out, int out_size, void* d_ws, size_t ws_size,
                              hipStream_t stream) {
  const float* h     = (const float*)d_in[0];
  const float* coord = (const float*)d_in[1];
  const float* vel   = (const float*)d_in[2];
  const int* edge_index = (const int*)d_in[3];
  const float* e_w1 = (const float*)d_in[4];
  const float* e_b1 = (const float*)d_in[5];
  const float* e_w2 = (const float*)d_in[6];
  const float* e_b2 = (const float*)d_in[7];
  const float* n_w1 = (const float*)d_in[8];
  const float* n_b1 = (const float*)d_in[9];
  const float* n_w2 = (const float*)d_in[10];
  const float* n_b2 = (const float*)d_in[11];
  const float* c_w1 = (const float*)d_in[12];
  const float* c_b1 = (const float*)d_in[13];
  const float* c_w  = (const float*)d_in[14];

  const int* rows = edge_index;
  const int* cols = edge_index + kEdges;

  float* h_out = (float*)d_out;
  float* coord_out = h_out + (size_t)kNodes * kNF;

  // ---- workspace layout (bytes) ----
  const size_t off_mbuf   = 0;                                       // E*64*2
  const size_t off_trans  = off_mbuf   + (size_t)kEdges * kHid * 2;  // E*16
  const size_t off_h16    = off_trans  + (size_t)kEdges * 16;        // N*64*2
  const size_t off_nodein = off_h16    + (size_t)kNodes * 64 * 2;    // N*128*2
  const size_t off_cv     = off_nodein + (size_t)kNodes * 128 * 2;   // N*32
  const size_t off_srows  = off_cv     + (size_t)kNodes * 32;        // E*4
  const size_t off_scols  = off_srows  + (size_t)kEdges * 4;         // E*4
  const size_t off_hist   = off_scols  + (size_t)kEdges * 4;         // N*4
  const size_t off_cursor = off_hist   + (size_t)kNodes * 4;         // N*4
  const size_t off_rowst  = off_cursor + (size_t)kNodes * 4;         // (N+1)*4 pad
  const size_t off_w1t    = off_rowst  + 200064;
  const size_t off_w2t    = off_w1t    + 64 * WR1 * 2;
  const size_t off_w3t    = off_w2t    + 64 * WR2 * 2;
  const size_t off_nw1t   = off_w3t    + 64 * WR2 * 2;
  const size_t off_nw2t   = off_nw1t   + 64 * WRN * 2;
  const size_t off_bsum   = off_nw2t   + 64 * WR2 * 2;
  const size_t off_boff   = off_bsum   + 256;
  const size_t need       = off_boff   + 256;

  char* ws = (char*)d_ws;

  if (ws_size >= need) {
    _Float16* mbuf    = (_Float16*)(ws + off_mbuf);
    float* transbuf   = (float*)(ws + off_trans);
    _Float16* h16     = (_Float16*)(ws + off_h16);
    _Float16* nodein  = (_Float16*)(ws + off_nodein);
    float4* cv        = (float4*)(ws + off_cv);
    int* srows        = (int*)(ws + off_srows);
    int* scols        = (int*)(ws + off_scols);
    int* hist         = (int*)(ws + off_hist);
    int* cursor       = (int*)(ws + off_cursor);
    int* rowstart     = (int*)(ws + off_rowst);
    _Float16* w1t     = (_Float16*)(ws + off_w1t);
    _Float16* w2t     = (_Float16*)(ws + off_w2t);
    _Float16* w3t     = (_Float16*)(ws + off_w3t);
    _Float16* nw1t    = (_Float16*)(ws + off_nw1t);
    _Float16* nw2t    = (_Float16*)(ws + off_nw2t);
    int* bsum         = (int*)(ws + off_bsum);
    int* boff         = (int*)(ws + off_boff);

    hipMemsetAsync(ws + off_hist, 0, (size_t)kNodes * 4 * 2, stream);  // hist+cursor

    prep_weights<<<42, 256, 0, stream>>>(e_w1, e_w2, c_w1, n_w1, n_w2,
                                         w1t, w2t, w3t, nw1t, nw2t);
    prep_nodes<<<(kNodes * 64 + 255) / 256, 256, 0, stream>>>(
        h, coord, vel, h16, nodein, cv);

    hist_kernel<<<(kEdges + 255) / 256, 256, 0, stream>>>(rows, hist);
    const int nb = (kNodes + 1023) / 1024;
    scan1<<<nb, 1024, 0, stream>>>(hist, rowstart, bsum);
    scan2<<<1, 64, 0, stream>>>(bsum, boff, rowstart);
    scan3<<<nb, 1024, 0, stream>>>(rowstart, boff);
    scatter_kernel<<<(kEdges + 255) / 256, 256, 0, stream>>>(
        rows, cols, rowstart, cursor, srows, scols);

    egnn_edge_mfma<<<kEdges / 64, 256, 0, stream>>>(
        h16, cv, srows, scols, w1t, w2t, w3t,
        e_b1, e_b2, c_b1, c_w, mbuf, transbuf);

    egnn_gather_kernel<<<(kNodes + 3) / 4, 256, 0, stream>>>(
        mbuf, transbuf, rowstart, nodein, coord_out);

    egnn_node_mfma<<<(kNodes + 63) / 64, 256, 0, stream>>>(
        nodein, nw1t, nw2t, n_b1, n_b2, h_out);
  } else {
    float* agg = (float*)d_ws;
    float* seg = agg + (size_t)kNodes * kHid;
    float* cnt = seg + (size_t)kNodes * 3;
    hipMemsetAsync(d_ws, 0, (size_t)kNodes * (kHid + 4) * sizeof(float), stream);

    egnn_edge_atomic<<<(kEdges + 255) / 256, 256, 0, stream>>>(
        h, coord, vel, rows, cols, e_w1, e_b1, e_w2, e_b2, c_w1, c_b1, c_w,
        agg, seg, cnt);

    egnn_node_fallback_kernel<<<(kNodes + 255) / 256, 256, 0, stream>>>(
        h, agg, seg, cnt, n_w1, n_b1, n_w2, n_b2, h_out, coord_out);
  }
}